// Round 3
// baseline (143.493 us; speedup 1.0000x reference)
//
#include <hip/hip_runtime.h>
#include <math.h>

#define TEMPORAL_W 0.8f
#define LOG2E 1.4426950408889634f
#define LN2   0.6931471805599453f

// ~18 VALU inst, 3 hardware transcendentals (v_exp_f32, v_log_f32, v_rcp_f32).
__device__ __forceinline__ float elem_loss(float x, int t) {
    const float a = fabsf(x);
    const float e = __builtin_amdgcn_exp2f(a * -LOG2E);        // exp(-|x|), e in (0,1]
    const float L = LN2 * __builtin_amdgcn_logf(1.0f + e);     // log1p(e); arg in (1,2]
    // BCE-with-logits: max(x,0) - x*t + log1p(exp(-|x|))
    const float bce = fmaxf(x, 0.0f) - (t ? x : 0.0f) + L;
    // pt = sigmoid agrees with target ? 1/(1+e) : e/(1+e); -log(pt) = L or a+L
    const bool agree = (x >= 0.0f) == (t != 0);
    const float r  = __builtin_amdgcn_rcpf(1.0f + e);
    const float pt = agree ? r : e * r;
    const float mlogpt = agree ? L : (a + L);                  // = -log(pt); EPS negligible
    const float om = 1.0f - pt;
    // combined = 0.5*bce + 0.5*(alpha * om^2 * mlogpt), alpha=0.25
    return 0.5f * (bce + 0.25f * om * om * mlogpt);
}

__global__ __launch_bounds__(256) void loss_fused_kernel(
        const float* __restrict__ x, const int* __restrict__ tg,
        float* __restrict__ partial, unsigned int* __restrict__ counter,
        float* __restrict__ out, int n8, int n, float invN) {
    const int tid    = blockIdx.x * blockDim.x + threadIdx.x;
    const int stride = gridDim.x * blockDim.x;
    float sum = 0.0f;

    const float4* x4 = reinterpret_cast<const float4*>(x);
    const int4*   t4 = reinterpret_cast<const int4*>(tg);

    for (int i = tid; i < n8; i += stride) {
        // elements e0..e3 = ta, e4..e7 = tb at global base 8*i
        const float4 xa = x4[2 * i];
        const float4 xb = x4[2 * i + 1];
        const int4   ta = t4[2 * i];
        const int4   tb = t4[2 * i + 1];

        int P1 = 0, P2 = 0, P3 = 0, P4 = 0, P5 = 0;  // tg[8i-1..8i-5]
        if (i > 0) {
            const int4 pv = t4[2 * i - 1];
            P1 = pv.w; P2 = pv.z; P3 = pv.y; P4 = pv.x;
            P5 = tg[8 * i - 5];                       // L1/L2 hit
        }

        // prefix-ORs for the 5-wide causal window (targets are 0/1)
        const int q2 = P1 | P2, q3 = q2 | P3, q4 = q3 | P4;
        const int s1 = ta.x | ta.y, s2 = s1 | ta.z, s3 = s2 | ta.w;
        const int w0 = q4 | P5;
        const int w1 = ta.x | q4;
        const int w2 = s1 | q3;
        const int w3 = s2 | q2;
        const int w4 = s3 | P1;
        const int w5 = tb.x | s3;
        const int w6 = tb.y | tb.x | ta.w | ta.z | ta.y;
        const int w7 = tb.z | tb.y | tb.x | ta.w | ta.z;

        float c0 = elem_loss(xa.x, ta.x);
        float c1 = elem_loss(xa.y, ta.y);
        float c2 = elem_loss(xa.z, ta.z);
        float c3 = elem_loss(xa.w, ta.w);
        float c4 = elem_loss(xb.x, tb.x);
        float c5 = elem_loss(xb.y, tb.y);
        float c6 = elem_loss(xb.z, tb.z);
        float c7 = elem_loss(xb.w, tb.w);

        c0 *= (ta.x & w0) ? TEMPORAL_W : 1.0f;
        c1 *= (ta.y & w1) ? TEMPORAL_W : 1.0f;
        c2 *= (ta.z & w2) ? TEMPORAL_W : 1.0f;
        c3 *= (ta.w & w3) ? TEMPORAL_W : 1.0f;
        c4 *= (tb.x & w4) ? TEMPORAL_W : 1.0f;
        c5 *= (tb.y & w5) ? TEMPORAL_W : 1.0f;
        c6 *= (tb.z & w6) ? TEMPORAL_W : 1.0f;
        c7 *= (tb.w & w7) ? TEMPORAL_W : 1.0f;

        sum += ((c0 + c1) + (c2 + c3)) + ((c4 + c5) + (c6 + c7));
    }

    // scalar tail for n not divisible by 8
    for (int g = 8 * n8 + tid; g < n; g += stride) {
        const int t = tg[g];
        int any = 0;
        #pragma unroll
        for (int k = 1; k <= 5; ++k) if (g - k >= 0) any |= tg[g - k];
        float c = elem_loss(x[g], t);
        if (t && any) c *= TEMPORAL_W;
        sum += c;
    }

    // intra-block reduction: wave shfl, then LDS across 4 waves
    #pragma unroll
    for (int off = 32; off > 0; off >>= 1) sum += __shfl_down(sum, off);
    __shared__ float wsum[4];
    __shared__ int   s_last;
    const int lane = threadIdx.x & 63;
    const int wid  = threadIdx.x >> 6;
    if (lane == 0) wsum[wid] = sum;
    __syncthreads();

    if (threadIdx.x == 0) {
        const float bsum = (wsum[0] + wsum[1]) + (wsum[2] + wsum[3]);
        // agent-scope release store: visible across XCDs (non-coherent L2s, G16)
        __hip_atomic_store(&partial[blockIdx.x], bsum,
                           __ATOMIC_RELEASE, __HIP_MEMORY_SCOPE_AGENT);
        const unsigned old = __hip_atomic_fetch_add(counter, 1u,
                           __ATOMIC_ACQ_REL, __HIP_MEMORY_SCOPE_AGENT);
        s_last = (old == gridDim.x - 1);
    }
    __syncthreads();

    if (s_last) {
        // last-arriving block: all partials are published; sum in fixed order
        float s = 0.0f;
        const int nb = gridDim.x;
        for (int i = threadIdx.x; i < nb; i += blockDim.x)
            s += __hip_atomic_load(&partial[i],
                                   __ATOMIC_RELAXED, __HIP_MEMORY_SCOPE_AGENT);
        #pragma unroll
        for (int off = 32; off > 0; off >>= 1) s += __shfl_down(s, off);
        __syncthreads();                       // reuse wsum safely
        if (lane == 0) wsum[wid] = s;
        __syncthreads();
        if (threadIdx.x == 0)
            out[0] = ((wsum[0] + wsum[1]) + (wsum[2] + wsum[3])) * invN;
    }
}

extern "C" void kernel_launch(void* const* d_in, const int* in_sizes, int n_in,
                              void* d_out, int out_size, void* d_ws, size_t ws_size,
                              hipStream_t stream) {
    const float* x  = (const float*)d_in[0];
    const int*   tg = (const int*)d_in[1];
    float* out      = (float*)d_out;

    const int NB = 2048;
    float*        partial = (float*)d_ws;
    unsigned int* counter = (unsigned int*)((char*)d_ws + (size_t)NB * sizeof(float));

    const int n  = in_sizes[0];
    const int n8 = n / 8;

    // zero the arrival counter each call (graph-capturable async memset)
    hipMemsetAsync(counter, 0, sizeof(unsigned int), stream);
    loss_fused_kernel<<<NB, 256, 0, stream>>>(x, tg, partial, counter, out,
                                              n8, n, 1.0f / (float)n);
}

// Round 4
// 31.091 us; speedup vs baseline: 4.6153x; 4.6153x over previous
//
#include <hip/hip_runtime.h>
#include <math.h>

#define TEMPORAL_W 0.8f
#define LOG2E 1.4426950408889634f
#define LN2   0.6931471805599453f

// ~18 VALU inst, 3 hardware transcendentals (v_exp_f32, v_log_f32, v_rcp_f32).
__device__ __forceinline__ float elem_loss(float x, int t) {
    const float a = fabsf(x);
    const float e = __builtin_amdgcn_exp2f(a * -LOG2E);        // exp(-|x|), e in (0,1]
    const float L = LN2 * __builtin_amdgcn_logf(1.0f + e);     // log1p(e); arg in (1,2]
    // BCE-with-logits: max(x,0) - x*t + log1p(exp(-|x|))
    const float bce = fmaxf(x, 0.0f) - (t ? x : 0.0f) + L;
    // pt = sigmoid agrees with target ? 1/(1+e) : e/(1+e); -log(pt) = L or a+L
    const bool agree = (x >= 0.0f) == (t != 0);
    const float r  = __builtin_amdgcn_rcpf(1.0f + e);
    const float pt = agree ? r : e * r;
    const float mlogpt = agree ? L : (a + L);                  // = -log(pt); EPS negligible
    const float om = 1.0f - pt;
    // combined = 0.5*bce + 0.5*(alpha * om^2 * mlogpt), alpha=0.25
    return 0.5f * (bce + 0.25f * om * om * mlogpt);
}

// 8 contiguous elements (xa|xb, ta|tb) with the 5 preceding targets P1..P5
// (P1 = immediately previous, P5 = 5 back). Returns the reweighted loss sum.
__device__ __forceinline__ float block8(const float4& xa, const float4& xb,
                                        const int4& ta, const int4& tb,
                                        int P1, int P2, int P3, int P4, int P5) {
    const int q2 = P1 | P2, q3 = q2 | P3, q4 = q3 | P4;
    const int s1 = ta.x | ta.y, s2 = s1 | ta.z, s3 = s2 | ta.w;
    const int w0 = q4 | P5;
    const int w1 = ta.x | q4;
    const int w2 = s1 | q3;
    const int w3 = s2 | q2;
    const int w4 = s3 | P1;
    const int w5 = tb.x | s3;
    const int w6 = tb.y | tb.x | ta.w | ta.z | ta.y;
    const int w7 = tb.z | tb.y | tb.x | ta.w | ta.z;

    float c0 = elem_loss(xa.x, ta.x);
    float c1 = elem_loss(xa.y, ta.y);
    float c2 = elem_loss(xa.z, ta.z);
    float c3 = elem_loss(xa.w, ta.w);
    float c4 = elem_loss(xb.x, tb.x);
    float c5 = elem_loss(xb.y, tb.y);
    float c6 = elem_loss(xb.z, tb.z);
    float c7 = elem_loss(xb.w, tb.w);

    c0 *= (ta.x & w0) ? TEMPORAL_W : 1.0f;
    c1 *= (ta.y & w1) ? TEMPORAL_W : 1.0f;
    c2 *= (ta.z & w2) ? TEMPORAL_W : 1.0f;
    c3 *= (ta.w & w3) ? TEMPORAL_W : 1.0f;
    c4 *= (tb.x & w4) ? TEMPORAL_W : 1.0f;
    c5 *= (tb.y & w5) ? TEMPORAL_W : 1.0f;
    c6 *= (tb.z & w6) ? TEMPORAL_W : 1.0f;
    c7 *= (tb.w & w7) ? TEMPORAL_W : 1.0f;

    return ((c0 + c1) + (c2 + c3)) + ((c4 + c5) + (c6 + c7));
}

__global__ __launch_bounds__(256) void loss_partial_kernel(
        const float* __restrict__ x, const int* __restrict__ tg,
        float* __restrict__ partial, int n16, int n) {
    const int tid    = blockIdx.x * blockDim.x + threadIdx.x;
    const int stride = gridDim.x * blockDim.x;
    float sum = 0.0f;

    const float4* x4 = reinterpret_cast<const float4*>(x);
    const int4*   t4 = reinterpret_cast<const int4*>(tg);

    for (int i = tid; i < n16; i += stride) {
        // 16 elements per iteration: issue all 8 vector loads up front (MLP)
        const float4 xa = x4[4 * i];
        const float4 xb = x4[4 * i + 1];
        const float4 xc = x4[4 * i + 2];
        const float4 xd = x4[4 * i + 3];
        const int4   ta = t4[4 * i];
        const int4   tb = t4[4 * i + 1];
        const int4   tc = t4[4 * i + 2];
        const int4   td = t4[4 * i + 3];

        int P1 = 0, P2 = 0, P3 = 0, P4 = 0, P5 = 0;  // tg[16i-1 .. 16i-5]
        if (i > 0) {
            const int4 pv = t4[4 * i - 1];
            P1 = pv.w; P2 = pv.z; P3 = pv.y; P4 = pv.x;
            P5 = tg[16 * i - 5];                      // L1/L2 hit
        }

        // first 8 elements: window from memory; second 8: window from registers
        sum += block8(xa, xb, ta, tb, P1, P2, P3, P4, P5);
        sum += block8(xc, xd, tc, td, tb.w, tb.z, tb.y, tb.x, ta.w);
    }

    // scalar tail for n not divisible by 16
    for (int g = 16 * n16 + tid; g < n; g += stride) {
        const int t = tg[g];
        int any = 0;
        #pragma unroll
        for (int k = 1; k <= 5; ++k) if (g - k >= 0) any |= tg[g - k];
        float c = elem_loss(x[g], t);
        if (t && any) c *= TEMPORAL_W;
        sum += c;
    }

    // wave (64-lane) reduction, then cross-wave via LDS
    #pragma unroll
    for (int off = 32; off > 0; off >>= 1) sum += __shfl_down(sum, off);
    __shared__ float wsum[4];
    const int lane = threadIdx.x & 63;
    const int wid  = threadIdx.x >> 6;
    if (lane == 0) wsum[wid] = sum;
    __syncthreads();
    if (threadIdx.x == 0)
        partial[blockIdx.x] = (wsum[0] + wsum[1]) + (wsum[2] + wsum[3]);
}

__global__ __launch_bounds__(256) void final_reduce_kernel(
        const float* __restrict__ partial, int nb,
        float* __restrict__ out, float invN) {
    float s = 0.0f;
    for (int i = threadIdx.x; i < nb; i += 256) s += partial[i];
    #pragma unroll
    for (int off = 32; off > 0; off >>= 1) s += __shfl_down(s, off);
    __shared__ float wsum[4];
    const int lane = threadIdx.x & 63;
    const int wid  = threadIdx.x >> 6;
    if (lane == 0) wsum[wid] = s;
    __syncthreads();
    if (threadIdx.x == 0)
        out[0] = ((wsum[0] + wsum[1]) + (wsum[2] + wsum[3])) * invN;
}

extern "C" void kernel_launch(void* const* d_in, const int* in_sizes, int n_in,
                              void* d_out, int out_size, void* d_ws, size_t ws_size,
                              hipStream_t stream) {
    const float* x  = (const float*)d_in[0];
    const int*   tg = (const int*)d_in[1];
    float* out      = (float*)d_out;
    float* partial  = (float*)d_ws;

    const int n   = in_sizes[0];
    const int n16 = n / 16;
    const int NB  = 2048;   // 8 wg/CU on 256 CUs = 32 waves/CU; grid-stride the rest

    loss_partial_kernel<<<NB, 256, 0, stream>>>(x, tg, partial, n16, n);
    final_reduce_kernel<<<1, 256, 0, stream>>>(partial, NB, out, 1.0f / (float)n);
}